// Round 4
// baseline (3582.351 us; speedup 1.0000x reference)
//
#include <hip/hip_runtime.h>
#include <hip/hip_fp16.h>
#include <math.h>

#define N_NODES  200000
#define N_EDGES  6400000
#define N_GRAPHS 64
#define NPB      128                      // nodes per bucket
#define NB       1563                     // ceil(N_NODES / NPB)
#define NCTR     (NB * 8)                 // per-(bucket, dispatch-group) counters
#define SCAN_CHUNK_CTR 49                 // 256*49 >= NCTR

typedef unsigned long long ull;
typedef unsigned int uint;

static __device__ inline unsigned short f2h_bits(float f) {
  __half h = __float2half(f);
  return *reinterpret_cast<unsigned short*>(&h);
}
static __device__ inline float hbits2f(unsigned short b) {
  __half h = *reinterpret_cast<__half*>(&b);
  return __half2float(h);
}

// ---------------------------------------------------------------------------
// Precompute g = node_feat @ W1a[4:11,:]  (N x 32, fp16). 8 nodes per block.
// ---------------------------------------------------------------------------
__global__ __launch_bounds__(256) void proj_g(
    const float* __restrict__ node_feat,
    const float* __restrict__ W1a,
    __half* __restrict__ g16) {
  __shared__ float sW[7 * 32];
  for (int i = threadIdx.x; i < 7 * 32; i += 256) sW[i] = W1a[4 * 32 + i];
  __syncthreads();
  int n = blockIdx.x * 8 + (threadIdx.x >> 5);   // grid 25000 -> exact
  int lane = threadIdx.x & 31;
  const float* nf = node_feat + (size_t)n * 7;
  float a = 0.0f;
#pragma unroll
  for (int k = 0; k < 7; ++k) a += nf[k] * sW[k * 32 + lane];
  g16[(size_t)n * 32 + lane] = __float2half(a);
}

// ---------------------------------------------------------------------------
// Bucket histogram: counter (b, g) where b = dst>>7, g = blockIdx&7.
// Must use the same e -> g mapping as bucket_scatter.
// ---------------------------------------------------------------------------
__global__ __launch_bounds__(256) void bucket_hist(
    const int* __restrict__ dst, uint* __restrict__ bhist) {
  int e = blockIdx.x * 256 + threadIdx.x;        // grid 25000 -> exact
  int b = dst[e] >> 7;
  int g = blockIdx.x & 7;
  atomicAdd(&bhist[b * 8 + g], 1u);
}

// ---------------------------------------------------------------------------
// Exclusive scan over the NCTR counters (single block). base kept for the
// aggregation kernels; bcur is the scatter cursor copy.
// ---------------------------------------------------------------------------
__global__ __launch_bounds__(256) void scan_ctr(
    const uint* __restrict__ bhist,
    uint* __restrict__ base, uint* __restrict__ bcur) {
  __shared__ uint s[256];
  int t = threadIdx.x;
  int i0 = t * SCAN_CHUNK_CTR;
  uint sum = 0;
  for (int k = 0; k < SCAN_CHUNK_CTR; ++k) {
    int i = i0 + k;
    if (i < NCTR) sum += bhist[i];
  }
  s[t] = sum;
  __syncthreads();
  for (int off = 1; off < 256; off <<= 1) {
    uint x = (t >= off) ? s[t - off] : 0u;
    __syncthreads();
    s[t] += x;
    __syncthreads();
  }
  uint run = s[t] - sum;
  for (int k = 0; k < SCAN_CHUNK_CTR; ++k) {
    int i = i0 + k;
    if (i < NCTR) {
      uint v = bhist[i];
      base[i] = run;
      bcur[i] = run;
      run += v;
    }
  }
}

// ---------------------------------------------------------------------------
// Bucket scatter. Per edge: write bs = (src<<7)|ln (4B) and bef = fp16x4
// edge features (8B) at the per-(bucket, group) cursor. Group = blockIdx&7
// keeps each sub-region's lines hot in a single XCD's L2 (write-amp ~1x).
// edge_feat is read COALESCED here (e-order) so nobody gathers it later.
// ---------------------------------------------------------------------------
__global__ __launch_bounds__(256) void bucket_scatter(
    const int* __restrict__ src,
    const int* __restrict__ dst,
    const float* __restrict__ edge_feat,
    uint* __restrict__ bcur,
    uint* __restrict__ bs,
    ull* __restrict__ bef) {
  int e = blockIdx.x * 256 + threadIdx.x;        // grid 25000 -> exact
  int d = dst[e];
  int sv = src[e];
  const float4 ef = *reinterpret_cast<const float4*>(edge_feat + (size_t)e * 4);
  int b = d >> 7;
  int ln = d & 127;
  int g = blockIdx.x & 7;
  uint pos = atomicAdd(&bcur[b * 8 + g], 1u);
  bs[pos] = ((uint)sv << 7) | (uint)ln;
  ull pk = (ull)f2h_bits(ef.x) | ((ull)f2h_bits(ef.y) << 16) |
           ((ull)f2h_bits(ef.z) << 32) | ((ull)f2h_bits(ef.w) << 48);
  bef[pos] = pk;
}

// ---------------------------------------------------------------------------
// Layer 1 aggregation + MLP1. One block per bucket; LDS accumulators
// acc[128][32]; 32-lane groups stream records, gather g16[src] rows
// (lane = feature -> coalesced 64B, ds_add bank = lane -> conflict-free).
// ---------------------------------------------------------------------------
__global__ __launch_bounds__(256) void agg1_mlp1(
    const uint* __restrict__ bs,
    const ull* __restrict__ bef,
    const uint* __restrict__ base,
    const __half* __restrict__ g16,
    const float* __restrict__ W1a, const float* __restrict__ b1a,
    const float* __restrict__ W1b, const float* __restrict__ b1b,
    __half* __restrict__ h1) {
  __shared__ float accg[NPB][32];    // 16 KB
  __shared__ float accef[NPB][4];    // 2 KB
  __shared__ uint  scnt[NPB];
  __shared__ float sWef[4 * 32];
  __shared__ float sW1b[32 * 32];
  __shared__ float sb1a[32], sb1b[32];
  for (int i = threadIdx.x; i < 4 * 32; i += 256) sWef[i] = W1a[i];
  for (int i = threadIdx.x; i < 32 * 32; i += 256) sW1b[i] = W1b[i];
  if (threadIdx.x < 32) {
    sb1a[threadIdx.x] = b1a[threadIdx.x];
    sb1b[threadIdx.x] = b1b[threadIdx.x];
  }
  for (int i = threadIdx.x; i < NPB * 32; i += 256) ((float*)accg)[i] = 0.0f;
  for (int i = threadIdx.x; i < NPB * 4; i += 256) ((float*)accef)[i] = 0.0f;
  for (int i = threadIdx.x; i < NPB; i += 256) scnt[i] = 0u;
  __syncthreads();

  const int b = blockIdx.x;
  const uint start = base[b * 8];
  const uint end = (b == NB - 1) ? (uint)N_EDGES : base[(b + 1) * 8];
  const int lane = threadIdx.x & 31;
  const int grp = threadIdx.x >> 5;

  for (uint ofs = start + (uint)grp * 32; ofs < end; ofs += 256) {
    uint m = min(32u, end - ofs);
    uint mybs = 0; ull myef = 0;
    if (lane < (int)m) {
      mybs = bs[ofs + lane];
      myef = bef[ofs + lane];
    }
    // per-lane: edge-feature + count accumulation for the lane's own edge
    if (lane < (int)m) {
      int lnl = (int)(mybs & 127u);
      atomicAdd(&scnt[lnl], 1u);
      atomicAdd(&accef[lnl][0], hbits2f((unsigned short)(myef)));
      atomicAdd(&accef[lnl][1], hbits2f((unsigned short)(myef >> 16)));
      atomicAdd(&accef[lnl][2], hbits2f((unsigned short)(myef >> 32)));
      atomicAdd(&accef[lnl][3], hbits2f((unsigned short)(myef >> 48)));
    }
    // group-wide g-row gathers, 4 in flight
    uint j = 0;
    for (; j + 4 <= m; j += 4) {
      uint r0 = __shfl(mybs, (int)(j + 0), 32);
      uint r1 = __shfl(mybs, (int)(j + 1), 32);
      uint r2 = __shfl(mybs, (int)(j + 2), 32);
      uint r3 = __shfl(mybs, (int)(j + 3), 32);
      float v0 = __half2float(g16[(size_t)(r0 >> 7) * 32 + lane]);
      float v1 = __half2float(g16[(size_t)(r1 >> 7) * 32 + lane]);
      float v2 = __half2float(g16[(size_t)(r2 >> 7) * 32 + lane]);
      float v3 = __half2float(g16[(size_t)(r3 >> 7) * 32 + lane]);
      atomicAdd(&accg[r0 & 127u][lane], v0);
      atomicAdd(&accg[r1 & 127u][lane], v1);
      atomicAdd(&accg[r2 & 127u][lane], v2);
      atomicAdd(&accg[r3 & 127u][lane], v3);
    }
    for (; j < m; ++j) {
      uint r = __shfl(mybs, (int)j, 32);
      float v = __half2float(g16[(size_t)(r >> 7) * 32 + lane]);
      atomicAdd(&accg[r & 127u][lane], v);
    }
  }
  __syncthreads();

  // MLP1: 8 groups x 16 nodes
  for (int q = 0; q < 16; ++q) {
    int ln = (grp << 4) + q;
    int n = b * NPB + ln;
    if (n >= N_NODES) break;
    float c = (float)scnt[ln];
    float inv = 1.0f / fmaxf(c, 1.0f);
    float u = accg[ln][lane] * inv;
    float m0 = accef[ln][0] * inv, m1 = accef[ln][1] * inv;
    float m2 = accef[ln][2] * inv, m3 = accef[ln][3] * inv;
    u += m0 * sWef[0 * 32 + lane] + m1 * sWef[1 * 32 + lane] +
         m2 * sWef[2 * 32 + lane] + m3 * sWef[3 * 32 + lane];
    u = fmaxf(u + sb1a[lane], 0.0f);
    float h = sb1b[lane];
#pragma unroll
    for (int i = 0; i < 32; ++i) h += __shfl(u, i, 32) * sW1b[i * 32 + lane];
    h1[(size_t)n * 32 + lane] = __float2half(fmaxf(h, 0.0f));
  }
}

// ---------------------------------------------------------------------------
// Layer 2 aggregation + MLP2 + per-graph max pool. Only reads bs (4B/edge)
// sequentially + h1 row gathers. Pool flushes batched by run of equal gid.
// ---------------------------------------------------------------------------
__global__ __launch_bounds__(256) void agg2_mlp2_pool(
    const uint* __restrict__ bs,
    const uint* __restrict__ base,
    const __half* __restrict__ h1,
    const int* __restrict__ graph_ids,
    const float* __restrict__ W2a, const float* __restrict__ b2a,
    const float* __restrict__ W2b, const float* __restrict__ b2b,
    uint* __restrict__ pooled_u) {
  __shared__ float acc[NPB][32];     // 16 KB
  __shared__ uint  scnt[NPB];
  __shared__ float sW2a[32 * 32], sW2b[32 * 32];
  __shared__ float sb2a[32], sb2b[32];
  for (int i = threadIdx.x; i < 32 * 32; i += 256) {
    sW2a[i] = W2a[i];
    sW2b[i] = W2b[i];
  }
  if (threadIdx.x < 32) {
    sb2a[threadIdx.x] = b2a[threadIdx.x];
    sb2b[threadIdx.x] = b2b[threadIdx.x];
  }
  for (int i = threadIdx.x; i < NPB * 32; i += 256) ((float*)acc)[i] = 0.0f;
  for (int i = threadIdx.x; i < NPB; i += 256) scnt[i] = 0u;
  __syncthreads();

  const int b = blockIdx.x;
  const uint start = base[b * 8];
  const uint end = (b == NB - 1) ? (uint)N_EDGES : base[(b + 1) * 8];
  const int lane = threadIdx.x & 31;
  const int grp = threadIdx.x >> 5;

  for (uint ofs = start + (uint)grp * 32; ofs < end; ofs += 256) {
    uint m = min(32u, end - ofs);
    uint mybs = 0;
    if (lane < (int)m) {
      mybs = bs[ofs + lane];
      atomicAdd(&scnt[mybs & 127u], 1u);
    }
    uint j = 0;
    for (; j + 4 <= m; j += 4) {
      uint r0 = __shfl(mybs, (int)(j + 0), 32);
      uint r1 = __shfl(mybs, (int)(j + 1), 32);
      uint r2 = __shfl(mybs, (int)(j + 2), 32);
      uint r3 = __shfl(mybs, (int)(j + 3), 32);
      float v0 = __half2float(h1[(size_t)(r0 >> 7) * 32 + lane]);
      float v1 = __half2float(h1[(size_t)(r1 >> 7) * 32 + lane]);
      float v2 = __half2float(h1[(size_t)(r2 >> 7) * 32 + lane]);
      float v3 = __half2float(h1[(size_t)(r3 >> 7) * 32 + lane]);
      atomicAdd(&acc[r0 & 127u][lane], v0);
      atomicAdd(&acc[r1 & 127u][lane], v1);
      atomicAdd(&acc[r2 & 127u][lane], v2);
      atomicAdd(&acc[r3 & 127u][lane], v3);
    }
    for (; j < m; ++j) {
      uint r = __shfl(mybs, (int)j, 32);
      float v = __half2float(h1[(size_t)(r >> 7) * 32 + lane]);
      atomicAdd(&acc[r & 127u][lane], v);
    }
  }
  __syncthreads();

  // MLP2 + pool: 8 groups x 16 nodes, run-length-batched atomicMax
  int rung = -1;
  float runmax = 0.0f;
  for (int q = 0; q < 16; ++q) {
    int ln = (grp << 4) + q;
    int n = b * NPB + ln;
    if (n >= N_NODES) break;
    float c = (float)scnt[ln];
    float inv = 1.0f / fmaxf(c, 1.0f);
    float mfeat = acc[ln][lane] * inv;
    float t = sb2a[lane];
#pragma unroll
    for (int i = 0; i < 32; ++i) t += __shfl(mfeat, i, 32) * sW2a[i * 32 + lane];
    t = fmaxf(t, 0.0f);
    float h = sb2b[lane];
#pragma unroll
    for (int i = 0; i < 32; ++i) h += __shfl(t, i, 32) * sW2b[i * 32 + lane];
    h = fmaxf(h, 0.0f);
    int g = graph_ids[n];
    if (g != rung) {
      if (rung >= 0)
        atomicMax(pooled_u + (size_t)rung * 32 + lane, __float_as_uint(runmax));
      rung = g;
      runmax = h;
    } else {
      runmax = fmaxf(runmax, h);
    }
  }
  if (rung >= 0)
    atomicMax(pooled_u + (size_t)rung * 32 + lane, __float_as_uint(runmax));
}

// ---------------------------------------------------------------------------
__global__ __launch_bounds__(64) void classifier(
    const uint* __restrict__ pooled_u,
    const float* __restrict__ Wm1, const float* __restrict__ bm1,
    const float* __restrict__ Wm2, const float* __restrict__ bm2,
    float* __restrict__ out) {
  int g = threadIdx.x;
  if (g >= N_GRAPHS) return;
  float p[32];
#pragma unroll
  for (int i = 0; i < 32; ++i) p[i] = __uint_as_float(pooled_u[(size_t)g * 32 + i]);
  float t[16];
#pragma unroll
  for (int j = 0; j < 16; ++j) {
    float acc = bm1[j];
#pragma unroll
    for (int i = 0; i < 32; ++i) acc += p[i] * Wm1[i * 16 + j];
    t[j] = fmaxf(acc, 0.0f);
  }
  float l0 = bm2[0], l1 = bm2[1];
#pragma unroll
  for (int i = 0; i < 16; ++i) {
    l0 += t[i] * Wm2[i * 2 + 0];
    l1 += t[i] * Wm2[i * 2 + 1];
  }
  float mx = fmaxf(l0, l1);
  float e0 = expf(l0 - mx), e1 = expf(l1 - mx);
  float s = e0 + e1;
  out[g * 2 + 0] = e0 / s;
  out[g * 2 + 1] = e1 / s;
}

// ---------------------------------------------------------------------------
extern "C" void kernel_launch(void* const* d_in, const int* in_sizes, int n_in,
                              void* d_out, int out_size, void* d_ws, size_t ws_size,
                              hipStream_t stream) {
  const float* node_feat = (const float*)d_in[0];
  const float* edge_feat = (const float*)d_in[1];
  const int*   src       = (const int*)d_in[2];
  const int*   dst       = (const int*)d_in[3];
  const int*   graph_ids = (const int*)d_in[4];
  const float* W1a = (const float*)d_in[5],  *b1a = (const float*)d_in[6];
  const float* W1b = (const float*)d_in[7],  *b1b = (const float*)d_in[8];
  const float* W2a = (const float*)d_in[9],  *b2a = (const float*)d_in[10];
  const float* W2b = (const float*)d_in[11], *b2b = (const float*)d_in[12];
  const float* Wm1 = (const float*)d_in[13], *bm1 = (const float*)d_in[14];
  const float* Wm2 = (const float*)d_in[15], *bm2 = (const float*)d_in[16];
  float* out = (float*)d_out;

  char* ws = (char*)d_ws;
  size_t off = 0;
  auto take = [&](size_t bytes) {
    char* p = ws + off;
    off = (off + bytes + 255) & ~(size_t)255;
    return p;
  };
  uint*   bhist    = (uint*)take((size_t)NCTR * 4);            // zeroed
  uint*   pooled_u = (uint*)take((size_t)N_GRAPHS * 32 * 4);   // zeroed
  size_t zero_bytes = off;
  uint*   base     = (uint*)take((size_t)NCTR * 4);
  uint*   bcur     = (uint*)take((size_t)NCTR * 4);
  uint*   bs       = (uint*)take((size_t)N_EDGES * 4);         // 25.6 MB
  ull*    bef      = (ull*)take((size_t)N_EDGES * 8);          // 51.2 MB
  __half* g16      = (__half*)take((size_t)N_NODES * 32 * 2);  // 12.8 MB
  __half* h1       = (__half*)take((size_t)N_NODES * 32 * 2);  // 12.8 MB
  (void)ws_size; (void)in_sizes; (void)n_in; (void)out_size;

  hipMemsetAsync(d_ws, 0, zero_bytes, stream);

  const int egrid = N_EDGES / 256;   // 25000, exact
  const int ngrid = N_NODES / 8;     // 25000, exact

  hipLaunchKernelGGL(proj_g, dim3(ngrid), dim3(256), 0, stream, node_feat, W1a, g16);
  hipLaunchKernelGGL(bucket_hist, dim3(egrid), dim3(256), 0, stream, dst, bhist);
  hipLaunchKernelGGL(scan_ctr, dim3(1), dim3(256), 0, stream, bhist, base, bcur);
  hipLaunchKernelGGL(bucket_scatter, dim3(egrid), dim3(256), 0, stream,
                     src, dst, edge_feat, bcur, bs, bef);
  hipLaunchKernelGGL(agg1_mlp1, dim3(NB), dim3(256), 0, stream,
                     bs, bef, base, g16, W1a, b1a, W1b, b1b, h1);
  hipLaunchKernelGGL(agg2_mlp2_pool, dim3(NB), dim3(256), 0, stream,
                     bs, base, h1, graph_ids, W2a, b2a, W2b, b2b, pooled_u);
  hipLaunchKernelGGL(classifier, dim3(1), dim3(64), 0, stream,
                     pooled_u, Wm1, bm1, Wm2, bm2, out);
}